// Round 15
// baseline (676.628 us; speedup 1.0000x reference)
//
#include <hip/hip_runtime.h>
#include <hip/hip_fp16.h>

// EdgeEmbAttentionAggregator — R7 (resubmit R15; R7-R14 benches failed on
// GPU acquisition — no counters). Counted-vmcnt deep prefetch (T3/T4).
// Algebra: score_s = sx + ng_s·w2a + ee_s·a_e  (sx = in·(W@a_x), w2a = W2@a_n)
// h' = agg@W2 (agg stored f16 in out h' slot, overwritten by post_gemm).
// vs R6: 3-slot LDS ring, prefetch depth 2 pairs, per-iteration
// s_waitcnt vmcnt(24) (= "next slot arrived") instead of vmcnt(0) — loads
// never drain to 0 in the main loop. Theory: R6's 5.5us/iter period was
// contended-latency-bound (depth-1 prefetch); delivery alone is ~2.6us.
// Audits (r8-r10): store-inclusive vmcnt window holds; raw s_barrier has
// no vmcnt(0) drain; immediates fit 6-bit field; tail clamps idempotent;
// 512 blocks resident at 2/CU.

#define BAR() do {                                              \
    asm volatile("s_waitcnt lgkmcnt(0)" ::: "memory");          \
    __builtin_amdgcn_s_barrier();                               \
    asm volatile("" ::: "memory");                               \
} while (0)

#define GLDS16(gp, lp) __builtin_amdgcn_global_load_lds(                     \
    (const __attribute__((address_space(1))) void*)(gp),                     \
    (__attribute__((address_space(3))) void*)(lp), 16, 0, 0)
#define GLDS4(gp, lp)  __builtin_amdgcn_global_load_lds(                     \
    (const __attribute__((address_space(1))) void*)(gp),                     \
    (__attribute__((address_space(3))) void*)(lp), 4, 0, 0)

__device__ __forceinline__ float dot4(float4 a, float4 b) {
    return fmaf(a.x, b.x, fmaf(a.y, b.y, fmaf(a.z, b.z, a.w * b.w)));
}

// ws layout (fp32): [0:128) w2a=W2@a_n ; [128:288) a copy ; [288:416) Wa=W@a_x
__global__ __launch_bounds__(256)
void prep_kernel(const float* __restrict__ W,
                 const float* __restrict__ W2,
                 const float* __restrict__ a,
                 float* __restrict__ ws) {
    const int t = threadIdx.x;
    __shared__ float s_a[160];
    if (t < 160) { float v = a[t]; s_a[t] = v; ws[128 + t] = v; }
    __syncthreads();
    if (t < 128) {
        float p = 0.f, pw = 0.f;
        #pragma unroll
        for (int d = 0; d < 64; d++) {
            p  = fmaf(W2[t * 64 + d], s_a[64 + d], p);
            pw = fmaf(W [t * 64 + d], s_a[d],      pw);
        }
        ws[t] = p;
        ws[288 + t] = pw;
    }
}

// 12 global_load_lds per node (8 ng16 + 2 ee16 + 2 in4) -> 24 per pair.
__device__ __forceinline__ void dma_node(const float* __restrict__ neigh,
                                         const float* __restrict__ edge,
                                         const float* __restrict__ input,
                                         int node, int lane,
                                         float* ng, float* ee, float* inb) {
    const float* gn = neigh + (size_t)node * 2048;
    #pragma unroll
    for (int i = 0; i < 8; i++) GLDS16(gn + i * 256 + lane * 4, ng + i * 256);
    const float* ge = edge + (size_t)node * 512;
    #pragma unroll
    for (int i = 0; i < 2; i++) GLDS16(ge + i * 256 + lane * 4, ee + i * 256);
    const float* gi = input + (size_t)node * 128;
    #pragma unroll
    for (int i = 0; i < 2; i++) GLDS4(gi + i * 64 + lane, inb + i * 64);
}

__global__ __launch_bounds__(256, 2)
void gat_attn(const float* __restrict__ input,
              const float* __restrict__ neigh,
              const float* __restrict__ edge,
              const float* __restrict__ ws,
              float* __restrict__ out, int N) {
    const int t = threadIdx.x;
    const int q = t >> 6;
    const int lane = t & 63;

    __shared__ __align__(16) float s_w2a[128];
    __shared__ __align__(16) float s_wa[128];
    __shared__ __align__(16) float s_ae[32];
    __shared__ __align__(16) float s_ng[3][2][2048];  // [slot][node] 16x128
    __shared__ __align__(16) float s_ee[3][2][512];   // 16x32
    __shared__ __align__(16) float s_in[3][2][128];
    __shared__ __align__(16) float s_sc[32];          // [node*16 + s]
    __shared__ float s_sx[2];

    if (t < 128) { s_w2a[t] = ws[t]; s_wa[t] = ws[288 + t]; }
    else if (t < 160) s_ae[t - 128] = ws[128 + t];    // ws[256:288) = a_e

    const int P = (N + 1) >> 1;       // node pairs
    const int stride = gridDim.x;
    int p = blockIdx.x;
    int sl = 0;                        // current ring slot

    // ---- prologue: wave 3 DMAs pair p -> slot0, pair p+stride -> slot1,
    // then waits for slot0 only (newest 24 = slot1 may stay in flight).
    if (q == 3 && p < P) {
        dma_node(neigh, edge, input, 2 * p, lane,
                 s_ng[0][0], s_ee[0][0], s_in[0][0]);
        dma_node(neigh, edge, input, min(2 * p + 1, N - 1), lane,
                 s_ng[0][1], s_ee[0][1], s_in[0][1]);
        const int p1 = min(p + stride, P - 1);
        dma_node(neigh, edge, input, 2 * p1, lane,
                 s_ng[1][0], s_ee[1][0], s_in[1][0]);
        dma_node(neigh, edge, input, min(2 * p1 + 1, N - 1), lane,
                 s_ng[1][1], s_ee[1][1], s_in[1][1]);
        asm volatile("s_waitcnt vmcnt(24)" ::: "memory");
    }
    BAR();   // also covers s_w2a/s_wa/s_ae

    for (; p < P; p += stride) {
        const int nA = 2 * p;
        const int nB = min(2 * p + 1, N - 1);
        const int s2 = sl < 1 ? sl + 2 : sl - 1;   // (sl+2)%3

        // ---- wave 3: issue depth-2 prefetch (clamped at tail to keep the
        // vmcnt-count invariant: exactly 24 newest outstanding loads)
        if (q == 3) {
            const int p2 = min(p + 2 * stride, P - 1);
            dma_node(neigh, edge, input, 2 * p2, lane,
                     s_ng[s2][0], s_ee[s2][0], s_in[s2][0]);
            dma_node(neigh, edge, input, min(2 * p2 + 1, N - 1), lane,
                     s_ng[s2][1], s_ee[s2][1], s_in[s2][1]);
            // sx for current pair (slot sl is guaranteed arrived)
            const float2 ia = ((const float2*)s_in[sl][0])[lane];
            const float2 ib = ((const float2*)s_in[sl][1])[lane];
            const float2 w  = ((const float2*)s_wa)[lane];
            float pa = fmaf(ia.x, w.x, ia.y * w.y);
            float pb = fmaf(ib.x, w.x, ib.y * w.y);
            #pragma unroll
            for (int off = 32; off; off >>= 1) {
                pa += __shfl_xor(pa, off, 64);
                pb += __shfl_xor(pb, off, 64);
            }
            if (lane == 0) { s_sx[0] = pa; s_sx[1] = pb; }
        }

        // ---- Phase B: pre-scores (no sx), 32 rows x 8 lanes
        {
            const int r = t >> 3, g = t & 7;       // r: [node*16 + s]
            const int node = r >> 4, s = r & 15;
            const float4* ng4  = (const float4*)(s_ng[sl][node] + s * 128);
            const float4* w2a4 = (const float4*)s_w2a;
            float pp = dot4(ng4[g],      w2a4[g])
                     + dot4(ng4[g + 8],  w2a4[g + 8])
                     + dot4(ng4[g + 16], w2a4[g + 16])
                     + dot4(ng4[g + 24], w2a4[g + 24]);
            pp += dot4(((const float4*)(s_ee[sl][node] + s * 32))[g],
                       ((const float4*)s_ae)[g]);
            pp += __shfl_down(pp, 4, 8);
            pp += __shfl_down(pp, 2, 8);
            pp += __shfl_down(pp, 1, 8);
            if (g == 0) s_sc[r] = pp;
        }
        BAR();   // BAR1

        // ---- Phase C: wave q -> node q&1, column-half q>>1
        {
            const int node = q & 1, half = q >> 1;
            const int n = node ? nB : nA;
            const float sx = s_sx[node];
            float e[16];
            #pragma unroll
            for (int j = 0; j < 4; j++) {
                float4 v = ((const float4*)s_sc)[node * 4 + j];
                v.x += sx; v.y += sx; v.z += sx; v.w += sx;
                e[4*j+0] = v.x > 0.f ? v.x : 0.8f * v.x;
                e[4*j+1] = v.y > 0.f ? v.y : 0.8f * v.y;
                e[4*j+2] = v.z > 0.f ? v.z : 0.8f * v.z;
                e[4*j+3] = v.w > 0.f ? v.w : 0.8f * v.w;
            }
            float m[8];
            #pragma unroll
            for (int i = 0; i < 8; i++) m[i] = fmaxf(e[i], e[i + 8]);
            #pragma unroll
            for (int i = 0; i < 4; i++) m[i] = fmaxf(m[i], m[i + 4]);
            const float mx = fmaxf(fmaxf(m[0], m[2]), fmaxf(m[1], m[3]));
            #pragma unroll
            for (int s = 0; s < 16; s++) e[s] = __expf(e[s] - mx);
            float sm[8];
            #pragma unroll
            for (int i = 0; i < 8; i++) sm[i] = e[i] + e[i + 8];
            #pragma unroll
            for (int i = 0; i < 4; i++) sm[i] = sm[i] + sm[i + 4];
            const float rinv = 1.0f / ((sm[0] + sm[2]) + (sm[1] + sm[3]));

            if (lane < 20) {
                const int fc = half * 20 + lane;   // f4-column 0..39
                if (fc < 32) {                      // neigh cols -> agg (f16)
                    const float4* col = (const float4*)s_ng[sl][node] + fc;
                    float4 acc = make_float4(0.f, 0.f, 0.f, 0.f);
                    #pragma unroll
                    for (int s = 0; s < 16; s++) {
                        const float4 v = col[s * 32];
                        acc.x = fmaf(e[s], v.x, acc.x);
                        acc.y = fmaf(e[s], v.y, acc.y);
                        acc.z = fmaf(e[s], v.z, acc.z);
                        acc.w = fmaf(e[s], v.w, acc.w);
                    }
                    union { __half2 h[2]; float2 f; } u;
                    u.h[0] = __floats2half2_rn(acc.x * rinv, acc.y * rinv);
                    u.h[1] = __floats2half2_rn(acc.z * rinv, acc.w * rinv);
                    ((float2*)(out + (size_t)n * 160 + 64))[fc] = u.f;
                } else {                            // edge cols -> h_edge (f32)
                    const int ec = fc - 32;
                    const float4* col = (const float4*)s_ee[sl][node] + ec;
                    float4 acc = make_float4(0.f, 0.f, 0.f, 0.f);
                    #pragma unroll
                    for (int s = 0; s < 16; s++) {
                        const float4 v = col[s * 8];
                        acc.x = fmaf(e[s], v.x, acc.x);
                        acc.y = fmaf(e[s], v.y, acc.y);
                        acc.z = fmaf(e[s], v.z, acc.z);
                        acc.w = fmaf(e[s], v.w, acc.w);
                    }
                    acc.x *= rinv; acc.y *= rinv; acc.z *= rinv; acc.w *= rinv;
                    *(float4*)(out + (size_t)n * 160 + 128 + (ec << 2)) = acc;
                }
            }
        }
        // counted wait: all but the newest 24 ops done => slot sl+1 arrived.
        // Never drains to 0 in the main loop (T4).
        if (q == 3) asm volatile("s_waitcnt vmcnt(24)" ::: "memory");
        BAR();   // BAR2
        sl = sl < 2 ? sl + 1 : 0;
    }
}

// K3: out[:,0:64) = input @ W ; out[:,64:128) = agg(f16,in out) @ W2 (in-place)
__global__ __launch_bounds__(256, 2)
void post_gemm(const float* __restrict__ input,
               const float* __restrict__ W,
               const float* __restrict__ W2,
               float* __restrict__ out, int N) {
    const int t = threadIdx.x;
    const int NB = (N + 63) >> 6;
    const bool second = ((int)blockIdx.x >= NB);
    const int rbase = (second ? blockIdx.x - NB : blockIdx.x) << 6;
    const int nrows = min(64, N - rbase);
    const float* Wsrc = second ? W2 : W;
    const int dstcol = second ? 64 : 0;

    __shared__ __align__(16) float sS[64 * 128];   // [r][k] 32KB
    __shared__ __align__(16) float sW[128 * 64];   // [k][c] 32KB

    #pragma unroll
    for (int i = 0; i < 8; i++) {
        const int idx = t + i * 256;
        ((float4*)sW)[idx] = ((const float4*)Wsrc)[idx];
    }
    if (!second) {
        #pragma unroll
        for (int i = 0; i < 8; i++) {
            const int idx = t + i * 256;
            const int r = idx >> 5;
            float4 v = make_float4(0.f, 0.f, 0.f, 0.f);
            if (r < nrows)
                v = ((const float4*)(input + (size_t)(rbase + r) * 128))[idx & 31];
            ((float4*)sS)[idx] = v;
        }
    } else {
        #pragma unroll
        for (int i = 0; i < 8; i++) {
            const int idx = t + i * 256;
            const int r = idx >> 5, j = idx & 31;
            float4 v = make_float4(0.f, 0.f, 0.f, 0.f);
            if (r < nrows) {
                union { float2 f; __half2 h[2]; } u;
                u.f = ((const float2*)(out + (size_t)(rbase + r) * 160 + 64))[j];
                const float2 lo = __half22float2(u.h[0]);
                const float2 hi = __half22float2(u.h[1]);
                v = make_float4(lo.x, lo.y, hi.x, hi.y);
            }
            ((float4*)sS)[idx] = v;
        }
    }
    __syncthreads();

    const int r0 = ((t >> 4) & 15) << 2, c0 = (t & 15) << 2;
    float4 acc0 = make_float4(0,0,0,0), acc1 = acc0, acc2 = acc0, acc3 = acc0;
    #pragma unroll 2
    for (int k4 = 0; k4 < 32; k4++) {
        const int k = k4 << 2;
        const float4 a0 = *(const float4*)(sS + (r0 + 0) * 128 + k);
        const float4 a1 = *(const float4*)(sS + (r0 + 1) * 128 + k);
        const float4 a2 = *(const float4*)(sS + (r0 + 2) * 128 + k);
        const float4 a3 = *(const float4*)(sS + (r0 + 3) * 128 + k);
        const float4 w0 = *(const float4*)(sW + (k + 0) * 64 + c0);
        const float4 w1 = *(const float4*)(sW + (k + 1) * 64 + c0);
        const float4 w2 = *(const float4*)(sW + (k + 2) * 64 + c0);
        const float4 w3 = *(const float4*)(sW + (k + 3) * 64 + c0);
        #define MADROW(ACC, A)                                              \
            ACC.x = fmaf(A.x, w0.x, ACC.x); ACC.y = fmaf(A.x, w0.y, ACC.y); \
            ACC.z = fmaf(A.x, w0.z, ACC.z); ACC.w = fmaf(A.x, w0.w, ACC.w); \
            ACC.x = fmaf(A.y, w1.x, ACC.x); ACC.y = fmaf(A.y, w1.y, ACC.y); \
            ACC.z = fmaf(A.y, w1.z, ACC.z); ACC.w = fmaf(A.y, w1.w, ACC.w); \
            ACC.x = fmaf(A.z, w2.x, ACC.x); ACC.y = fmaf(A.z, w2.y, ACC.y); \
            ACC.z = fmaf(A.z, w2.z, ACC.z); ACC.w = fmaf(A.z, w2.w, ACC.w); \
            ACC.x = fmaf(A.w, w3.x, ACC.x); ACC.y = fmaf(A.w, w3.y, ACC.y); \
            ACC.z = fmaf(A.w, w3.z, ACC.z); ACC.w = fmaf(A.w, w3.w, ACC.w);
        MADROW(acc0, a0) MADROW(acc1, a1) MADROW(acc2, a2) MADROW(acc3, a3)
        #undef MADROW
    }
    if (r0 + 0 < nrows) *(float4*)(out + (size_t)(rbase + r0 + 0) * 160 + dstcol + c0) = acc0;
    if (r0 + 1 < nrows) *(float4*)(out + (size_t)(rbase + r0 + 1) * 160 + dstcol + c0) = acc1;
    if (r0 + 2 < nrows) *(float4*)(out + (size_t)(rbase + r0 + 2) * 160 + dstcol + c0) = acc2;
    if (r0 + 3 < nrows) *(float4*)(out + (size_t)(rbase + r0 + 3) * 160 + dstcol + c0) = acc3;
}

extern "C" void kernel_launch(void* const* d_in, const int* in_sizes, int n_in,
                              void* d_out, int out_size, void* d_ws, size_t ws_size,
                              hipStream_t stream) {
    const float* input = (const float*)d_in[0];
    const float* neigh = (const float*)d_in[1];
    const float* edge  = (const float*)d_in[2];
    const float* W     = (const float*)d_in[3];
    const float* W2    = (const float*)d_in[4];
    const float* a     = (const float*)d_in[5];
    float* ws = (float*)d_ws;
    float* out = (float*)d_out;

    const int N = in_sizes[0] / 128;   // 50000
    const int NB = (N + 63) >> 6;      // 782

    prep_kernel<<<1, 256, 0, stream>>>(W, W2, a, ws);
    gat_attn<<<512, 256, 0, stream>>>(input, neigh, edge, ws, out, N);
    post_gemm<<<2 * NB, 256, 0, stream>>>(input, W, W2, out, N);
}